// Round 1
// baseline (3787.416 us; speedup 1.0000x reference)
//
#include <hip/hip_runtime.h>
#include <hip/hip_bf16.h>

#define WF 64

// ---------------- kernels ----------------

__global__ __launch_bounds__(256) void deg_kernel(const int* __restrict__ rows,
                                                  const float* __restrict__ vals,
                                                  float* __restrict__ deg, int E) {
    int e = blockIdx.x * blockDim.x + threadIdx.x;
    if (e < E) unsafeAtomicAdd(&deg[rows[e]], vals[e]);
}

__global__ __launch_bounds__(256) void invdeg_kernel(float* __restrict__ d1,
                                                     float* __restrict__ d2, int n) {
    int i = blockIdx.x * blockDim.x + threadIdx.x;
    if (i < n) {
        d1[i] = 1.0f / (d1[i] + 1e-8f);
        d2[i] = 1.0f / (d2[i] + 1e-8f);
    }
}

__global__ __launch_bounds__(256) void mark_kernel(const int* __restrict__ ids,
                                                   int* __restrict__ mark, int n) {
    int i = blockIdx.x * blockDim.x + threadIdx.x;
    if (i < n) mark[ids[i]] = 1;
}

// Edge-parallel SpMM scatter: 16 threads per edge, float4 per thread.
// acc[row] += (vals[e] * invdeg[row]) * feats[col]
template <bool MASKED>
__global__ __launch_bounds__(256) void spmm_kernel(const int* __restrict__ rows,
                                                   const int* __restrict__ cols,
                                                   const float* __restrict__ vals,
                                                   const float* __restrict__ invdeg,
                                                   const float* __restrict__ feats,
                                                   float* __restrict__ acc,
                                                   const int* __restrict__ mark, int E) {
    long long t = (long long)blockIdx.x * blockDim.x + threadIdx.x;
    int e = (int)(t >> 4);
    if (e >= E) return;
    int r = rows[e];
    if (MASKED && mark[r] == 0) return;
    int c = ((int)t & 15) * 4;
    float s = vals[e] * invdeg[r];
    const float4 f = *(const float4*)&feats[(long long)cols[e] * 64 + c];
    float* a = &acc[(long long)r * 64 + c];
    unsafeAtomicAdd(a + 0, s * f.x);
    unsafeAtomicAdd(a + 1, s * f.y);
    unsafeAtomicAdd(a + 2, s * f.z);
    unsafeAtomicAdd(a + 3, s * f.w);
}

// h1 = acc1 + user_emb   (in place into acc1), float4 granularity
__global__ __launch_bounds__(256) void add_emb_kernel(float* __restrict__ acc,
                                                      const float* __restrict__ emb,
                                                      long long n4) {
    long long i = (long long)blockIdx.x * blockDim.x + threadIdx.x;
    if (i < n4) {
        float4 a = *(float4*)&acc[i * 4];
        float4 b = *(const float4*)&emb[i * 4];
        a.x += b.x; a.y += b.y; a.z += b.z; a.w += b.w;
        *(float4*)&acc[i * 4] = a;
    }
}

// out[i] = sigmoid( dot(2*h1[uid] + accF[uid], 2*item_emb[iid]) ), one wave per i
__global__ __launch_bounds__(256) void dot_kernel(const float* __restrict__ h1,
                                                  const float* __restrict__ accF,
                                                  const float* __restrict__ item_emb,
                                                  const int* __restrict__ uids,
                                                  const int* __restrict__ iids,
                                                  float* __restrict__ out, int batch) {
    int w = (int)((blockIdx.x * blockDim.x + threadIdx.x) >> 6);
    int lane = threadIdx.x & 63;
    if (w >= batch) return;
    int u = uids[w], it = iids[w];
    float uv = 2.0f * h1[(long long)u * 64 + lane] + accF[(long long)u * 64 + lane];
    float vv = 2.0f * item_emb[(long long)it * 64 + lane];
    float p = uv * vv;
    #pragma unroll
    for (int off = 32; off; off >>= 1) p += __shfl_xor(p, off);
    if (lane == 0) out[w] = 1.0f / (1.0f + __expf(-p));
}

// ---------------- launch ----------------

extern "C" void kernel_launch(void* const* d_in, const int* in_sizes, int n_in,
                              void* d_out, int out_size, void* d_ws, size_t ws_size,
                              hipStream_t stream) {
    const float* user_emb   = (const float*)d_in[0];
    const float* item_emb   = (const float*)d_in[1];
    const int*   soc_rows   = (const int*)d_in[2];
    const int*   soc_cols   = (const int*)d_in[3];
    const float* soc_vals   = (const float*)d_in[4];
    const int*   info_rows  = (const int*)d_in[5];
    const int*   info_cols  = (const int*)d_in[6];
    const float* info_vals  = (const float*)d_in[7];
    const int*   user_ids   = (const int*)d_in[8];
    const int*   item_ids   = (const int*)d_in[9];
    float*       out        = (float*)d_out;

    const int n_user = in_sizes[0] / 64;
    const int E_soc  = in_sizes[2];
    const int E_info = in_sizes[5];
    const int batch  = in_sizes[8];

    // workspace layout (floats)
    float* deg_soc  = (float*)d_ws;                 // n_user
    float* deg_info = deg_soc + n_user;             // n_user
    int*   mark     = (int*)(deg_info + n_user);    // n_user
    float* acc1     = (float*)(mark + n_user);      // n_user*64  (becomes h1)
    float* accF     = acc1 + (long long)n_user * 64;// n_user*64
    size_t used = (size_t)n_user * (3 + 128) * sizeof(float);
    (void)ws_size;

    hipMemsetAsync(d_ws, 0, used, stream);

    const int B = 256;
    // degrees
    deg_kernel<<<(E_soc + B - 1) / B, B, 0, stream>>>(soc_rows, soc_vals, deg_soc, E_soc);
    deg_kernel<<<(E_info + B - 1) / B, B, 0, stream>>>(info_rows, info_vals, deg_info, E_info);
    invdeg_kernel<<<(n_user + B - 1) / B, B, 0, stream>>>(deg_soc, deg_info, n_user);
    mark_kernel<<<(batch + B - 1) / B, B, 0, stream>>>(user_ids, mark, batch);

    // layer-1 social SpMM (full): acc1 += (v/deg)*user_emb[col]
    long long t1 = (long long)E_soc * 16;
    spmm_kernel<false><<<(t1 + B - 1) / B, B, 0, stream>>>(
        soc_rows, soc_cols, soc_vals, deg_soc, user_emb, acc1, nullptr, E_soc);
    // h1 = acc1 + user_emb
    long long n4 = (long long)n_user * 16;
    add_emb_kernel<<<(n4 + B - 1) / B, B, 0, stream>>>(acc1, user_emb, n4);

    // layer-2 social SpMM, restricted to marked rows: accF += (v/deg)*h1[col]
    spmm_kernel<true><<<(t1 + B - 1) / B, B, 0, stream>>>(
        soc_rows, soc_cols, soc_vals, deg_soc, acc1, accF, mark, E_soc);
    // info SpMM, restricted: accF += (v/deg_info)*item_emb[col]
    long long t2 = (long long)E_info * 16;
    spmm_kernel<true><<<(t2 + B - 1) / B, B, 0, stream>>>(
        info_rows, info_cols, info_vals, deg_info, item_emb, accF, mark, E_info);

    // epilogue: sigmoid(dot(2*h1+accF, 2*item_emb))
    long long tdot = (long long)batch * 64;
    dot_kernel<<<(tdot + B - 1) / B, B, 0, stream>>>(
        acc1, accF, item_emb, user_ids, item_ids, out, batch);
}

// Round 2
// 908.980 us; speedup vs baseline: 4.1667x; 4.1667x over previous
//
#include <hip/hip_runtime.h>
#include <hip/hip_bf16.h>

// ---------------- kernels ----------------

// Dedup-mark users appearing in user_ids and build a compact list of them.
__global__ __launch_bounds__(256) void mark_kernel(const int* __restrict__ ids,
                                                   int* __restrict__ mark,
                                                   int* __restrict__ mlist,
                                                   int* __restrict__ n_marked, int n) {
    int i = blockIdx.x * blockDim.x + threadIdx.x;
    if (i >= n) return;
    int u = ids[i];
    if (atomicExch(&mark[u], 1) == 0) mlist[atomicAdd(n_marked, 1)] = u;
}

// Per-row edge-count histogram (optionally restricted to marked rows).
template <bool MASKED>
__global__ __launch_bounds__(256) void hist_kernel(const int* __restrict__ rows,
                                                   int* __restrict__ cnt,
                                                   const int* __restrict__ mark, int E) {
    int e = blockIdx.x * blockDim.x + threadIdx.x;
    if (e >= E) return;
    int r = rows[e];
    if (MASKED && mark[r] == 0) return;
    atomicAdd(&cnt[r], 1);
}

// Exclusive scan of two count arrays (block 0 -> soc, block 1 -> info),
// writing start[] and initializing cursor[] = start[].
__global__ __launch_bounds__(1024) void scan_kernel(const int* __restrict__ cnt0,
                                                    int* __restrict__ start0, int* __restrict__ cur0,
                                                    const int* __restrict__ cnt1,
                                                    int* __restrict__ start1, int* __restrict__ cur1,
                                                    int n) {
    const int* cnt = blockIdx.x ? cnt1 : cnt0;
    int* start = blockIdx.x ? start1 : start0;
    int* cur   = blockIdx.x ? cur1 : cur0;
    __shared__ int wsum[16];
    int tid = threadIdx.x, lane = tid & 63, wid = tid >> 6;
    int carry = 0;
    for (int base = 0; base < n; base += 1024) {
        int i = base + tid;
        int x = (i < n) ? cnt[i] : 0;
        int v = x;
        #pragma unroll
        for (int d = 1; d < 64; d <<= 1) {
            int y = __shfl_up(v, d);
            if (lane >= d) v += y;
        }
        if (lane == 63) wsum[wid] = v;
        __syncthreads();
        if (wid == 0) {
            int s = (lane < 16) ? wsum[lane] : 0;
            #pragma unroll
            for (int d = 1; d < 16; d <<= 1) {
                int y = __shfl_up(s, d);
                if (lane >= d) s += y;
            }
            if (lane < 16) wsum[lane] = s;
        }
        __syncthreads();
        int woff = wid ? wsum[wid - 1] : 0;
        int excl = carry + woff + (v - x);
        if (i < n) { start[i] = excl; cur[i] = excl; }
        int tot = wsum[15];
        __syncthreads();
        carry += tot;
    }
}

// Scatter edges into CSR buckets: csr[p] = (col, val_bits).
template <bool MASKED>
__global__ __launch_bounds__(256) void scatter_kernel(const int* __restrict__ rows,
                                                      const int* __restrict__ cols,
                                                      const float* __restrict__ vals,
                                                      int* __restrict__ cursor,
                                                      int2* __restrict__ csr,
                                                      const int* __restrict__ mark, int E) {
    int e = blockIdx.x * blockDim.x + threadIdx.x;
    if (e >= E) return;
    int r = rows[e];
    if (MASKED && mark[r] == 0) return;
    int p = atomicAdd(&cursor[r], 1);
    csr[p] = make_int2(cols[e], __float_as_int(vals[e]));
}

// Layer-1 gather over all rows: h1[r] = (sum val*feats[col]) / (sum val + eps) + feats[r]
__global__ __launch_bounds__(256) void gather1_kernel(const int* __restrict__ start,
                                                      const int* __restrict__ cnt,
                                                      const int2* __restrict__ csr,
                                                      const float* __restrict__ feats,
                                                      float* __restrict__ h1, int n_rows) {
    int w = (int)((blockIdx.x * (long long)blockDim.x + threadIdx.x) >> 6);
    int lane = threadIdx.x & 63;
    if (w >= n_rows) return;
    int j0 = start[w], c = cnt[w];
    float acc = 0.f, degs = 0.f;
    for (int j = j0; j < j0 + c; ++j) {
        int2 e = csr[j];
        float v = __int_as_float(e.y);
        acc += v * feats[(long long)e.x * 64 + lane];
        degs += v;
    }
    float inv = 1.0f / (degs + 1e-8f);
    h1[(long long)w * 64 + lane] = acc * inv + feats[(long long)w * 64 + lane];
}

// Fused layer-2 social + info gather over marked rows only:
// accF[r] = spmm_soc(h1)[r]/deg_soc[r] + spmm_info(item_emb)[r]/deg_info[r]
__global__ __launch_bounds__(256) void gatherF_kernel(const int* __restrict__ mlist,
                                                      const int* __restrict__ n_marked,
                                                      const int* __restrict__ startS,
                                                      const int* __restrict__ cntS,
                                                      const int2* __restrict__ csrS,
                                                      const float* __restrict__ h1,
                                                      const int* __restrict__ startI,
                                                      const int* __restrict__ cntI,
                                                      const int2* __restrict__ csrI,
                                                      const float* __restrict__ item_emb,
                                                      float* __restrict__ accF) {
    int w = (int)((blockIdx.x * (long long)blockDim.x + threadIdx.x) >> 6);
    int lane = threadIdx.x & 63;
    if (w >= *n_marked) return;
    int r = mlist[w];

    float acc = 0.f, degs = 0.f;
    int j0 = startS[r], c = cntS[r];
    for (int j = j0; j < j0 + c; ++j) {
        int2 e = csrS[j];
        float v = __int_as_float(e.y);
        acc += v * h1[(long long)e.x * 64 + lane];
        degs += v;
    }
    float res = acc / (degs + 1e-8f);

    acc = 0.f; degs = 0.f;
    j0 = startI[r]; c = cntI[r];
    for (int j = j0; j < j0 + c; ++j) {
        int2 e = csrI[j];
        float v = __int_as_float(e.y);
        acc += v * item_emb[(long long)e.x * 64 + lane];
        degs += v;
    }
    res += acc / (degs + 1e-8f);

    accF[(long long)r * 64 + lane] = res;
}

// out[i] = sigmoid( dot(2*h1[uid] + accF[uid], 2*item_emb[iid]) ), one wave per pair
__global__ __launch_bounds__(256) void dot_kernel(const float* __restrict__ h1,
                                                  const float* __restrict__ accF,
                                                  const float* __restrict__ item_emb,
                                                  const int* __restrict__ uids,
                                                  const int* __restrict__ iids,
                                                  float* __restrict__ out, int batch) {
    int w = (int)((blockIdx.x * (long long)blockDim.x + threadIdx.x) >> 6);
    int lane = threadIdx.x & 63;
    if (w >= batch) return;
    int u = uids[w], it = iids[w];
    float uv = 2.0f * h1[(long long)u * 64 + lane] + accF[(long long)u * 64 + lane];
    float vv = 2.0f * item_emb[(long long)it * 64 + lane];
    float p = uv * vv;
    #pragma unroll
    for (int off = 32; off; off >>= 1) p += __shfl_xor(p, off);
    if (lane == 0) out[w] = 1.0f / (1.0f + __expf(-p));
}

// ---------------- launch ----------------

extern "C" void kernel_launch(void* const* d_in, const int* in_sizes, int n_in,
                              void* d_out, int out_size, void* d_ws, size_t ws_size,
                              hipStream_t stream) {
    const float* user_emb  = (const float*)d_in[0];
    const float* item_emb  = (const float*)d_in[1];
    const int*   soc_rows  = (const int*)d_in[2];
    const int*   soc_cols  = (const int*)d_in[3];
    const float* soc_vals  = (const float*)d_in[4];
    const int*   info_rows = (const int*)d_in[5];
    const int*   info_cols = (const int*)d_in[6];
    const float* info_vals = (const float*)d_in[7];
    const int*   user_ids  = (const int*)d_in[8];
    const int*   item_ids  = (const int*)d_in[9];
    float*       out       = (float*)d_out;

    const int n_user = in_sizes[0] / 64;
    const int E_soc  = in_sizes[2];
    const int E_info = in_sizes[5];
    const int batch  = in_sizes[8];

    // ---- workspace layout ----
    char* p = (char*)d_ws;
    auto alloc = [&](size_t bytes) { char* q = p; p += (bytes + 255) & ~size_t(255); return q; };
    // zeroed region (must be contiguous at front)
    int* cnt_soc  = (int*)alloc(sizeof(int) * n_user);
    int* cnt_info = (int*)alloc(sizeof(int) * n_user);
    int* mark     = (int*)alloc(sizeof(int) * n_user);
    int* n_marked = (int*)alloc(sizeof(int) * 64);
    size_t zero_bytes = (size_t)((char*)p - (char*)d_ws);
    // non-zeroed
    int*  start_soc  = (int*)alloc(sizeof(int) * n_user);
    int*  start_info = (int*)alloc(sizeof(int) * n_user);
    int*  cur_soc    = (int*)alloc(sizeof(int) * n_user);
    int*  cur_info   = (int*)alloc(sizeof(int) * n_user);
    int*  mlist      = (int*)alloc(sizeof(int) * n_user);
    int2* csr_soc    = (int2*)alloc(sizeof(int2) * (size_t)E_soc);
    int2* csr_info   = (int2*)alloc(sizeof(int2) * (size_t)E_info);
    float* h1        = (float*)alloc(sizeof(float) * (size_t)n_user * 64);
    float* accF      = (float*)alloc(sizeof(float) * (size_t)n_user * 64);
    (void)ws_size;

    hipMemsetAsync(d_ws, 0, zero_bytes, stream);

    const int B = 256;
    mark_kernel<<<(batch + B - 1) / B, B, 0, stream>>>(user_ids, mark, mlist, n_marked, batch);

    hist_kernel<false><<<(E_soc + B - 1) / B, B, 0, stream>>>(soc_rows, cnt_soc, nullptr, E_soc);
    hist_kernel<true><<<(E_info + B - 1) / B, B, 0, stream>>>(info_rows, cnt_info, mark, E_info);

    scan_kernel<<<2, 1024, 0, stream>>>(cnt_soc, start_soc, cur_soc,
                                        cnt_info, start_info, cur_info, n_user);

    scatter_kernel<false><<<(E_soc + B - 1) / B, B, 0, stream>>>(
        soc_rows, soc_cols, soc_vals, cur_soc, csr_soc, nullptr, E_soc);
    scatter_kernel<true><<<(E_info + B - 1) / B, B, 0, stream>>>(
        info_rows, info_cols, info_vals, cur_info, csr_info, mark, E_info);

    long long t1 = (long long)n_user * 64;
    gather1_kernel<<<(t1 + B - 1) / B, B, 0, stream>>>(start_soc, cnt_soc, csr_soc,
                                                       user_emb, h1, n_user);

    long long t2 = (long long)batch * 64;
    gatherF_kernel<<<(t2 + B - 1) / B, B, 0, stream>>>(mlist, n_marked,
                                                       start_soc, cnt_soc, csr_soc, h1,
                                                       start_info, cnt_info, csr_info, item_emb,
                                                       accF);

    dot_kernel<<<(t2 + B - 1) / B, B, 0, stream>>>(h1, accF, item_emb,
                                                   user_ids, item_ids, out, batch);
}

// Round 3
// 546.042 us; speedup vs baseline: 6.9361x; 1.6647x over previous
//
#include <hip/hip_runtime.h>
#include <hip/hip_bf16.h>

#define SCHUNK 1024

// ---------------- kernels ----------------

// Dedup-mark users appearing in user_ids and build a compact list of them.
__global__ __launch_bounds__(256) void mark_kernel(const int* __restrict__ ids,
                                                   int* __restrict__ mark,
                                                   int* __restrict__ mlist,
                                                   int* __restrict__ n_marked, int n) {
    int i = blockIdx.x * blockDim.x + threadIdx.x;
    if (i >= n) return;
    int u = ids[i];
    if (atomicExch(&mark[u], 1) == 0) mlist[atomicAdd(n_marked, 1)] = u;
}

// Fused histograms: soc (all rows) + info (marked rows only).
__global__ __launch_bounds__(256) void hist2_kernel(const int* __restrict__ soc_rows,
                                                    int* __restrict__ cnt_soc, int E_soc,
                                                    const int* __restrict__ info_rows,
                                                    const int* __restrict__ mark,
                                                    int* __restrict__ cnt_info, int E_info) {
    int e = blockIdx.x * blockDim.x + threadIdx.x;
    if (e < E_soc) atomicAdd(&cnt_soc[soc_rows[e]], 1);
    if (e < E_info) {
        int r = info_rows[e];
        if (mark[r]) atomicAdd(&cnt_info[r], 1);
    }
}

// Scan phase A: per-block sums of SCHUNK elements. grid=(nb,2).
__global__ __launch_bounds__(256) void scanA_kernel(const int* __restrict__ cnt0,
                                                    const int* __restrict__ cnt1,
                                                    int* __restrict__ bsum, int n, int nb) {
    const int* cnt = blockIdx.y ? cnt1 : cnt0;
    int base = blockIdx.x * SCHUNK;
    int tid = threadIdx.x;
    int lim = min(base + SCHUNK, n);
    int s = 0;
    for (int i = base + tid; i < lim; i += 256) s += cnt[i];
    #pragma unroll
    for (int d = 32; d; d >>= 1) s += __shfl_xor(s, d);
    __shared__ int ws[4];
    if ((tid & 63) == 0) ws[tid >> 6] = s;
    __syncthreads();
    if (tid == 0) bsum[blockIdx.y * nb + blockIdx.x] = ws[0] + ws[1] + ws[2] + ws[3];
}

// Scan phase B: exclusive scan of each array's nb block sums (one wave).
__global__ __launch_bounds__(64) void scanB_kernel(int* __restrict__ bsum, int nb) {
    int lane = threadIdx.x;
    for (int a = 0; a < 2; ++a) {
        int* b = bsum + a * nb;
        int carry = 0;
        for (int base = 0; base < nb; base += 64) {
            int i = base + lane;
            int x = (i < nb) ? b[i] : 0;
            int v = x;
            #pragma unroll
            for (int d = 1; d < 64; d <<= 1) { int y = __shfl_up(v, d); if (lane >= d) v += y; }
            if (i < nb) b[i] = carry + v - x;
            carry += __shfl(v, 63);
        }
    }
}

// Scan phase C: local exclusive scan + block offset; write start[] and cursor[].
__global__ __launch_bounds__(256) void scanC_kernel(const int* __restrict__ cnt0,
                                                    const int* __restrict__ cnt1,
                                                    const int* __restrict__ bsum,
                                                    int* __restrict__ start0, int* __restrict__ cur0,
                                                    int* __restrict__ start1, int* __restrict__ cur1,
                                                    int n, int nb) {
    const int* cnt = blockIdx.y ? cnt1 : cnt0;
    int* start = blockIdx.y ? start1 : start0;
    int* cur   = blockIdx.y ? cur1 : cur0;
    int base = blockIdx.x * SCHUNK;
    int tid = threadIdx.x, lane = tid & 63, wid = tid >> 6;
    __shared__ int ws[4];
    int carry = bsum[blockIdx.y * nb + blockIdx.x];
    for (int seg = 0; seg < SCHUNK; seg += 256) {
        int i = base + seg + tid;
        int x = (i < n) ? cnt[i] : 0;
        int v = x;
        #pragma unroll
        for (int d = 1; d < 64; d <<= 1) { int y = __shfl_up(v, d); if (lane >= d) v += y; }
        if (lane == 63) ws[wid] = v;
        __syncthreads();
        int woff = 0;
        if (wid > 0) woff = ws[0];
        if (wid > 1) woff += ws[1];
        if (wid > 2) woff += ws[2];
        int excl = carry + woff + v - x;
        if (i < n) { start[i] = excl; cur[i] = excl; }
        int tot = ws[0] + ws[1] + ws[2] + ws[3];
        __syncthreads();
        carry += tot;
    }
}

// Fused scatter into CSR buckets: csr[p] = (col, val_bits).
__global__ __launch_bounds__(256) void scatter2_kernel(const int* __restrict__ soc_rows,
                                                       const int* __restrict__ soc_cols,
                                                       const float* __restrict__ soc_vals,
                                                       int* __restrict__ cur_soc,
                                                       int2* __restrict__ csr_soc, int E_soc,
                                                       const int* __restrict__ info_rows,
                                                       const int* __restrict__ info_cols,
                                                       const float* __restrict__ info_vals,
                                                       const int* __restrict__ mark,
                                                       int* __restrict__ cur_info,
                                                       int2* __restrict__ csr_info, int E_info) {
    int e = blockIdx.x * blockDim.x + threadIdx.x;
    if (e < E_soc) {
        int r = soc_rows[e];
        int p = atomicAdd(&cur_soc[r], 1);
        csr_soc[p] = make_int2(soc_cols[e], __float_as_int(soc_vals[e]));
    }
    if (e < E_info) {
        int r = info_rows[e];
        if (mark[r]) {
            int p = atomicAdd(&cur_info[r], 1);
            csr_info[p] = make_int2(info_cols[e], __float_as_int(info_vals[e]));
        }
    }
}

// Layer-1 gather, 4 edges in flight per wave (16 lanes x float4 each).
// h1[r] = (sum val*feats[col]) / (sum val + eps) + feats[r]
__global__ __launch_bounds__(256) void gather1_kernel(const int* __restrict__ start,
                                                      const int* __restrict__ endp,
                                                      const int2* __restrict__ csr,
                                                      const float* __restrict__ feats,
                                                      float* __restrict__ h1, int n_rows) {
    int w = (int)((blockIdx.x * (long long)blockDim.x + threadIdx.x) >> 6);
    if (w >= n_rows) return;
    int lane = threadIdx.x & 63;
    int sub = lane >> 4;           // edge slot 0..3
    int d4  = (lane & 15) << 2;    // dim offset
    int j1 = endp[w];
    float4 acc = make_float4(0.f, 0.f, 0.f, 0.f);
    float degs = 0.f;
    for (int j = start[w] + sub; j < j1; j += 4) {
        int2 e = csr[j];
        float v = __int_as_float(e.y);
        const float4 f = *(const float4*)&feats[(long long)e.x * 64 + d4];
        acc.x += v * f.x; acc.y += v * f.y; acc.z += v * f.z; acc.w += v * f.w;
        degs += v;
    }
    #pragma unroll
    for (int m = 16; m < 64; m <<= 1) {
        acc.x += __shfl_xor(acc.x, m);
        acc.y += __shfl_xor(acc.y, m);
        acc.z += __shfl_xor(acc.z, m);
        acc.w += __shfl_xor(acc.w, m);
        degs  += __shfl_xor(degs, m);
    }
    if (sub == 0) {
        float inv = 1.0f / (degs + 1e-8f);
        const float4 fe = *(const float4*)&feats[(long long)w * 64 + d4];
        float4 o = make_float4(fmaf(acc.x, inv, fe.x), fmaf(acc.y, inv, fe.y),
                               fmaf(acc.z, inv, fe.z), fmaf(acc.w, inv, fe.w));
        *(float4*)&h1[(long long)w * 64 + d4] = o;
    }
}

// Fused layer-2 social + info gather over marked rows, same 4-edge ILP.
__global__ __launch_bounds__(256) void gatherF_kernel(const int* __restrict__ mlist,
                                                      const int* __restrict__ n_marked,
                                                      const int* __restrict__ startS,
                                                      const int* __restrict__ endS,
                                                      const int2* __restrict__ csrS,
                                                      const float* __restrict__ h1,
                                                      const int* __restrict__ startI,
                                                      const int* __restrict__ endI,
                                                      const int2* __restrict__ csrI,
                                                      const float* __restrict__ item_emb,
                                                      float* __restrict__ accF) {
    int w = (int)((blockIdx.x * (long long)blockDim.x + threadIdx.x) >> 6);
    if (w >= *n_marked) return;
    int lane = threadIdx.x & 63;
    int sub = lane >> 4;
    int d4  = (lane & 15) << 2;
    int r = mlist[w];

    float4 accA = make_float4(0.f, 0.f, 0.f, 0.f);
    float degA = 0.f;
    int j1 = endS[r];
    for (int j = startS[r] + sub; j < j1; j += 4) {
        int2 e = csrS[j];
        float v = __int_as_float(e.y);
        const float4 f = *(const float4*)&h1[(long long)e.x * 64 + d4];
        accA.x += v * f.x; accA.y += v * f.y; accA.z += v * f.z; accA.w += v * f.w;
        degA += v;
    }
    float4 accB = make_float4(0.f, 0.f, 0.f, 0.f);
    float degB = 0.f;
    j1 = endI[r];
    for (int j = startI[r] + sub; j < j1; j += 4) {
        int2 e = csrI[j];
        float v = __int_as_float(e.y);
        const float4 f = *(const float4*)&item_emb[(long long)e.x * 64 + d4];
        accB.x += v * f.x; accB.y += v * f.y; accB.z += v * f.z; accB.w += v * f.w;
        degB += v;
    }
    #pragma unroll
    for (int m = 16; m < 64; m <<= 1) {
        accA.x += __shfl_xor(accA.x, m); accA.y += __shfl_xor(accA.y, m);
        accA.z += __shfl_xor(accA.z, m); accA.w += __shfl_xor(accA.w, m);
        degA   += __shfl_xor(degA, m);
        accB.x += __shfl_xor(accB.x, m); accB.y += __shfl_xor(accB.y, m);
        accB.z += __shfl_xor(accB.z, m); accB.w += __shfl_xor(accB.w, m);
        degB   += __shfl_xor(degB, m);
    }
    if (sub == 0) {
        float invA = 1.0f / (degA + 1e-8f);
        float invB = 1.0f / (degB + 1e-8f);
        float4 o = make_float4(accA.x * invA + accB.x * invB,
                               accA.y * invA + accB.y * invB,
                               accA.z * invA + accB.z * invB,
                               accA.w * invA + accB.w * invB);
        *(float4*)&accF[(long long)r * 64 + d4] = o;
    }
}

// out[i] = sigmoid( dot(2*h1[uid] + accF[uid], 2*item_emb[iid]) ), one wave per pair
__global__ __launch_bounds__(256) void dot_kernel(const float* __restrict__ h1,
                                                  const float* __restrict__ accF,
                                                  const float* __restrict__ item_emb,
                                                  const int* __restrict__ uids,
                                                  const int* __restrict__ iids,
                                                  float* __restrict__ out, int batch) {
    int w = (int)((blockIdx.x * (long long)blockDim.x + threadIdx.x) >> 6);
    int lane = threadIdx.x & 63;
    if (w >= batch) return;
    int u = uids[w], it = iids[w];
    float uv = 2.0f * h1[(long long)u * 64 + lane] + accF[(long long)u * 64 + lane];
    float vv = 2.0f * item_emb[(long long)it * 64 + lane];
    float p = uv * vv;
    #pragma unroll
    for (int off = 32; off; off >>= 1) p += __shfl_xor(p, off);
    if (lane == 0) out[w] = 1.0f / (1.0f + __expf(-p));
}

// ---------------- launch ----------------

extern "C" void kernel_launch(void* const* d_in, const int* in_sizes, int n_in,
                              void* d_out, int out_size, void* d_ws, size_t ws_size,
                              hipStream_t stream) {
    const float* user_emb  = (const float*)d_in[0];
    const float* item_emb  = (const float*)d_in[1];
    const int*   soc_rows  = (const int*)d_in[2];
    const int*   soc_cols  = (const int*)d_in[3];
    const float* soc_vals  = (const float*)d_in[4];
    const int*   info_rows = (const int*)d_in[5];
    const int*   info_cols = (const int*)d_in[6];
    const float* info_vals = (const float*)d_in[7];
    const int*   user_ids  = (const int*)d_in[8];
    const int*   item_ids  = (const int*)d_in[9];
    float*       out       = (float*)d_out;

    const int n_user = in_sizes[0] / 64;
    const int E_soc  = in_sizes[2];
    const int E_info = in_sizes[5];
    const int batch  = in_sizes[8];
    const int nb     = (n_user + SCHUNK - 1) / SCHUNK;

    // ---- workspace layout ----
    char* p = (char*)d_ws;
    auto alloc = [&](size_t bytes) { char* q = p; p += (bytes + 255) & ~size_t(255); return q; };
    // zeroed region (contiguous at front)
    int* cnt_soc  = (int*)alloc(sizeof(int) * n_user);
    int* cnt_info = (int*)alloc(sizeof(int) * n_user);
    int* mark     = (int*)alloc(sizeof(int) * n_user);
    int* n_marked = (int*)alloc(sizeof(int) * 64);
    size_t zero_bytes = (size_t)(p - (char*)d_ws);
    // non-zeroed
    int*  start_soc  = (int*)alloc(sizeof(int) * n_user);
    int*  start_info = (int*)alloc(sizeof(int) * n_user);
    int*  cur_soc    = (int*)alloc(sizeof(int) * n_user);
    int*  cur_info   = (int*)alloc(sizeof(int) * n_user);
    int*  mlist      = (int*)alloc(sizeof(int) * n_user);
    int*  bsum       = (int*)alloc(sizeof(int) * 2 * nb);
    int2* csr_soc    = (int2*)alloc(sizeof(int2) * (size_t)E_soc);
    int2* csr_info   = (int2*)alloc(sizeof(int2) * (size_t)E_info);
    float* h1        = (float*)alloc(sizeof(float) * (size_t)n_user * 64);
    float* accF      = (float*)alloc(sizeof(float) * (size_t)n_user * 64);
    (void)ws_size;

    hipMemsetAsync(d_ws, 0, zero_bytes, stream);

    const int B = 256;
    mark_kernel<<<(batch + B - 1) / B, B, 0, stream>>>(user_ids, mark, mlist, n_marked, batch);

    int Emax = max(E_soc, E_info);
    hist2_kernel<<<(Emax + B - 1) / B, B, 0, stream>>>(soc_rows, cnt_soc, E_soc,
                                                       info_rows, mark, cnt_info, E_info);

    scanA_kernel<<<dim3(nb, 2), B, 0, stream>>>(cnt_soc, cnt_info, bsum, n_user, nb);
    scanB_kernel<<<1, 64, 0, stream>>>(bsum, nb);
    scanC_kernel<<<dim3(nb, 2), B, 0, stream>>>(cnt_soc, cnt_info, bsum,
                                                start_soc, cur_soc, start_info, cur_info,
                                                n_user, nb);

    scatter2_kernel<<<(Emax + B - 1) / B, B, 0, stream>>>(
        soc_rows, soc_cols, soc_vals, cur_soc, csr_soc, E_soc,
        info_rows, info_cols, info_vals, mark, cur_info, csr_info, E_info);

    long long t1 = (long long)n_user * 64;
    gather1_kernel<<<(t1 + B - 1) / B, B, 0, stream>>>(start_soc, cur_soc, csr_soc,
                                                       user_emb, h1, n_user);

    long long t2 = (long long)batch * 64;
    gatherF_kernel<<<(t2 + B - 1) / B, B, 0, stream>>>(mlist, n_marked,
                                                       start_soc, cur_soc, csr_soc, h1,
                                                       start_info, cur_info, csr_info, item_emb,
                                                       accF);

    dot_kernel<<<(t2 + B - 1) / B, B, 0, stream>>>(h1, accF, item_emb,
                                                   user_ids, item_ids, out, batch);
}